// Round 6
// baseline (60.023 us; speedup 1.0000x reference)
//
#include <hip/hip_runtime.h>

// Problem constants (match reference)
#define BATCH 16
#define IMG_H 1024
#define IMG_W 1024
#define WORDS 16                              // 1024 cols / 64 bits
#define TOTAL_WORDS (BATCH * IMG_H * WORDS)   // 262144 (2 MiB as u64)
typedef unsigned long long u64;

// ===================== kernel 1: pack targets -> bitmask =====================
// Pure stream: 67MB read, 2MB write. No LDS, no barriers, grid-stride.
// Also zeroes the output accumulator (runs first on the stream).
#define PK_NT 256
#define PK_BLOCKS 2048
#define PK_WAVES (PK_NT / 64)                            // 4
#define GROUPS (TOTAL_WORDS / 4)                         // 65536 groups of 4 words
#define PK_ITERS (GROUPS / (PK_BLOCKS * PK_WAVES))       // 8

__global__ __launch_bounds__(PK_NT, 8)
void wbce_pack_kernel(const float* __restrict__ tgt, u64* __restrict__ pak,
                      float* __restrict__ out)
{
    if (blockIdx.x == 0 && threadIdx.x == 0) out[0] = 0.0f;
    const int lane = threadIdx.x & 63;
    const int gw   = blockIdx.x * PK_WAVES + (threadIdx.x >> 6);
    #pragma unroll
    for (int i = 0; i < PK_ITERS; ++i) {
        int g = gw + i * (PK_BLOCKS * PK_WAVES);         // word-group id
        const float* p = tgt + (size_t)g * 256 + lane;   // 4 words = 256 px
        float v0 = p[0], v1 = p[64], v2 = p[128], v3 = p[192];
        u64 m0 = __ballot(v0 > 0.5f);
        u64 m1 = __ballot(v1 > 0.5f);
        u64 m2 = __ballot(v2 > 0.5f);
        u64 m3 = __ballot(v3 > 0.5f);
        if (lane == 0) {
            ulonglong2* q = (ulonglong2*)(pak + (size_t)g * 4);
            q[0] = make_ulonglong2(m0, m1);
            q[1] = make_ulonglong2(m2, m3);
        }
    }
}

// ========== kernel 2: bitwise 9x9 morphology on packed words (tiny) ==========
// One thread per u64 word: fused horizontal(+-4 bit) + vertical(+-4 row)
// OR/AND from L2-resident 2MB array. Writes interleaved {target, boundary}
// u32 pairs as uint4 per word so the BCE kernel does ONE 8B side-load/float4.
#define MO_NT 256
__global__ __launch_bounds__(MO_NT, 8)
void wbce_morph_kernel(const u64* __restrict__ pak, uint4* __restrict__ tbnd)
{
    const int idx = blockIdx.x * MO_NT + threadIdx.x;    // word id [0, 262144)
    const int w   = idx & 15;
    const int row = (idx >> 4) & (IMG_H - 1);
    const int img = idx >> 14;
    const u64* ib = pak + (size_t)img * (IMG_H * WORDS);

    u64 d = 0ULL, e = ~0ULL, C = 0ULL;
    const int r0 = row >= 4 ? row - 4 : 0;               // OOB rows: neutral
    const int r1 = row <= IMG_H - 5 ? row + 4 : IMG_H - 1;
    for (int r = r0; r <= r1; ++r) {
        const u64* rp = ib + (size_t)r * WORDS;
        u64 c  = rp[w];
        u64 P  = (w > 0)  ? rp[w - 1] : 0ULL;            // OOB col: dilate fill 0
        u64 N  = (w < 15) ? rp[w + 1] : 0ULL;
        u64 Pe = (w > 0)  ? P : ~0ULL;                   // OOB col: erode fill 1
        u64 Ne = (w < 15) ? N : ~0ULL;
        u64 hd = c, he = c;
        #pragma unroll
        for (int s = 1; s <= 4; ++s) {
            hd |= (c >> s) | (N  << (64 - s));
            hd |= (c << s) | (P  >> (64 - s));
            he &= (c >> s) | (Ne << (64 - s));
            he &= (c << s) | (Pe >> (64 - s));
        }
        d |= hd;
        e &= he;
        if (r == row) C = c;
    }
    u64 bnd = d & ~e;                                    // boundary bits
    tbnd[idx] = make_uint4((unsigned)C,          (unsigned)bnd,
                           (unsigned)(C >> 32),  (unsigned)(bnd >> 32));
}

// ============ kernel 3: BCE stream + global reduce (pure stream) ============
// 67MB logits grid-stride, statically unrolled x8; one uint2 side-load per
// float4 (L2-hot, 8-lane broadcast). Barriers only in the final reduction.
#define BC_NT 256
#define BC_BLOCKS 2048
#define TOTAL_F4 (BATCH * IMG_H * IMG_W / 4)             // 4194304
#define BC_STRIDE (BC_NT * BC_BLOCKS)                    // 524288
#define BC_ITERS (TOTAL_F4 / BC_STRIDE)                  // 8
#define BC_NWAVES (BC_NT / 64)

__global__ __launch_bounds__(BC_NT, 6)
void wbce_bce_kernel(const float* __restrict__ logits,
                     const uint2* __restrict__ tbnd,     // uint4 array viewed as uint2
                     float* __restrict__ out)
{
    __shared__ float sRed[BC_NWAVES];
    const int tid = threadIdx.x;
    const int i0  = blockIdx.x * BC_NT + tid;
    const float4* lg4 = (const float4*)logits;

    float acc = 0.0f;
    #pragma unroll
    for (int k = 0; k < BC_ITERS; ++k) {
        int it = i0 + k * BC_STRIDE;                     // float4 index
        float4 x4 = lg4[it];
        uint2  tb = tbnd[it >> 3];                       // {target32, boundary32}
        int    sh = (it & 7) * 4;                        // 4-bit field in each u32

        const float xs[4] = {x4.x, x4.y, x4.z, x4.w};
        #pragma unroll
        for (int j = 0; j < 4; ++j) {
            unsigned tbit = (tb.x >> (sh + j)) & 1u;
            unsigned bbit = (tb.y >> (sh + j)) & 1u;
            unsigned xu   = __float_as_uint(xs[j]);
            // pe = softplus((1-2y)x) = max(sgn,0) + ln2*log2(1 + 2^(-|x|*log2e))
            float sgn = __uint_as_float(xu ^ (tbit << 31));
            float a   = __uint_as_float(xu & 0x7fffffffu);
            float t   = __builtin_exp2f(a * -1.44269504088896340736f);
            float l2  = __builtin_log2f(1.0f + t);
            float pe  = fmaf(l2, 0.69314718055994530942f, fmaxf(sgn, 0.0f));
            float wg  = fmaf((float)bbit, 2.0f, 1.0f);   // BOUNDARY_WEIGHT=3
            acc = fmaf(wg, pe, acc);
        }
    }

    // wave64 shuffle tree, then cross-wave via LDS, one atomic per block
    #pragma unroll
    for (int off = 32; off > 0; off >>= 1)
        acc += __shfl_down(acc, off, 64);
    const int lane = tid & 63, wv = tid >> 6;
    if (lane == 0) sRed[wv] = acc;
    __syncthreads();
    if (tid == 0) {
        float s = 0.0f;
        #pragma unroll
        for (int i = 0; i < BC_NWAVES; ++i) s += sRed[i];
        atomicAdd(out, s * (1.0f / 16777216.0f));        // mean: 1/2^24 exact
    }
}

extern "C" void kernel_launch(void* const* d_in, const int* in_sizes, int n_in,
                              void* d_out, int out_size, void* d_ws, size_t ws_size,
                              hipStream_t stream) {
    const float* logits  = (const float*)d_in[0];
    const float* targets = (const float*)d_in[1];
    float* out = (float*)d_out;

    // scratch layout: pak = 2 MiB of u64, tbnd = 4 MiB of uint4 (6 MiB total)
    u64*   pak  = (u64*)d_ws;
    uint4* tbnd = (uint4*)(pak + TOTAL_WORDS);

    // 1) pack targets (also zeroes out[0]; stream order guards the atomics)
    wbce_pack_kernel<<<dim3(PK_BLOCKS), dim3(PK_NT), 0, stream>>>(targets, pak, out);

    // 2) bitwise morphology on the 2MB packed array (L2-scale, ~2us)
    wbce_morph_kernel<<<dim3(TOTAL_WORDS / MO_NT), dim3(MO_NT), 0, stream>>>(pak, tbnd);

    // 3) BCE stream over logits + global mean reduce
    wbce_bce_kernel<<<dim3(BC_BLOCKS), dim3(BC_NT), 0, stream>>>(
        logits, (const uint2*)tbnd, out);
}

// Round 7
// 42.314 us; speedup vs baseline: 1.4185x; 1.4185x over previous
//
#include <hip/hip_runtime.h>

// Problem constants (match reference)
#define BATCH 16
#define IMG_H 1024
#define IMG_W 1024
#define WORDS 16                              // 1024 cols / 64 bits
#define TOTAL_WORDS (BATCH * IMG_H * WORDS)   // 262144 (2 MiB as u64)
typedef unsigned long long u64;

// ===================== kernel 1: pack targets -> bitmask =====================
// Pure stream, max TLP: 8192 blocks x 4 waves, 2 groups per wave, 4
// independent dword loads per group (MLP=4..8). 67MB read, 2MB write.
#define PK_NT 256
#define PK_BLOCKS 8192
#define PK_WAVES (PK_NT / 64)                            // 4
#define GROUPS (TOTAL_WORDS / 4)                         // 65536 groups of 4 words
#define PK_ITERS (GROUPS / (PK_BLOCKS * PK_WAVES))       // 2

__global__ __launch_bounds__(PK_NT, 8)
void wbce_pack_kernel(const float* __restrict__ tgt, u64* __restrict__ pak)
{
    const int lane = threadIdx.x & 63;
    const int gw   = blockIdx.x * PK_WAVES + (threadIdx.x >> 6);
    #pragma unroll
    for (int i = 0; i < PK_ITERS; ++i) {
        int g = gw + i * (PK_BLOCKS * PK_WAVES);         // word-group id
        const float* p = tgt + (size_t)g * 256 + lane;   // 4 words = 256 px
        float v0 = p[0], v1 = p[64], v2 = p[128], v3 = p[192];
        u64 m0 = __ballot(v0 > 0.5f);
        u64 m1 = __ballot(v1 > 0.5f);
        u64 m2 = __ballot(v2 > 0.5f);
        u64 m3 = __ballot(v3 > 0.5f);
        if (lane == 0) {
            ulonglong2* q = (ulonglong2*)(pak + (size_t)g * 4);
            q[0] = make_ulonglong2(m0, m1);
            q[1] = make_ulonglong2(m2, m3);
        }
    }
}

// ========== kernel 2: bitwise 9x9 morphology on packed words (tiny) ==========
// One thread per u64 word: fused horizontal(+-4 bit) + vertical(+-4 row)
// OR/AND on the L2-resident 2MB array. Writes interleaved {target, boundary}
// u32 pairs as uint4 per word so the BCE kernel does one 8B side-load/float4.
#define MO_NT 256
__global__ __launch_bounds__(MO_NT, 8)
void wbce_morph_kernel(const u64* __restrict__ pak, uint4* __restrict__ tbnd)
{
    const int idx = blockIdx.x * MO_NT + threadIdx.x;    // word id [0, 262144)
    const int w   = idx & 15;
    const int row = (idx >> 4) & (IMG_H - 1);
    const int img = idx >> 14;
    const u64* ib = pak + (size_t)img * (IMG_H * WORDS);

    u64 d = 0ULL, e = ~0ULL, C = 0ULL;
    const int r0 = row >= 4 ? row - 4 : 0;               // OOB rows: neutral
    const int r1 = row <= IMG_H - 5 ? row + 4 : IMG_H - 1;
    for (int r = r0; r <= r1; ++r) {
        const u64* rp = ib + (size_t)r * WORDS;
        u64 c  = rp[w];
        u64 P  = (w > 0)  ? rp[w - 1] : 0ULL;            // OOB col: dilate fill 0
        u64 N  = (w < 15) ? rp[w + 1] : 0ULL;
        u64 Pe = (w > 0)  ? P : ~0ULL;                   // OOB col: erode fill 1
        u64 Ne = (w < 15) ? N : ~0ULL;
        u64 hd = c, he = c;
        #pragma unroll
        for (int s = 1; s <= 4; ++s) {
            hd |= (c >> s) | (N  << (64 - s));
            hd |= (c << s) | (P  >> (64 - s));
            he &= (c >> s) | (Ne << (64 - s));
            he &= (c << s) | (Pe >> (64 - s));
        }
        d |= hd;
        e &= he;
        if (r == row) C = c;
    }
    u64 bnd = d & ~e;                                    // boundary bits
    tbnd[idx] = make_uint4((unsigned)C,          (unsigned)bnd,
                           (unsigned)(C >> 32),  (unsigned)(bnd >> 32));
}

// =========== kernel 3: BCE stream, straight-line (no loop to sink) ===========
// Each thread: 8 px = 2 float4 + 2 uint2, ALL loads issued at entry (MLP=4),
// latency hidden by TLP (8192 blocks, 32 waves/CU of work, VGPR ~32).
// Writes one partial per block -> no atomics, no zeroing.
#define BC_NT 256
#define BC_THREADS (BATCH * IMG_H * IMG_W / 8)           // 2097152 threads
#define BC_BLOCKS (BC_THREADS / BC_NT)                   // 8192
#define BC_NWAVES (BC_NT / 64)

__device__ __forceinline__ float bce4(float4 x4, unsigned tw, unsigned bw, int sh)
{
    float acc = 0.0f;
    const float xs[4] = {x4.x, x4.y, x4.z, x4.w};
    #pragma unroll
    for (int j = 0; j < 4; ++j) {
        unsigned tbit = (tw >> (sh + j)) & 1u;
        unsigned bbit = (bw >> (sh + j)) & 1u;
        unsigned xu   = __float_as_uint(xs[j]);
        // pe = softplus((1-2y)x) = max(sgn,0) + ln2*log2(1 + 2^(-|x|*log2e))
        float sgn = __uint_as_float(xu ^ (tbit << 31));
        float a   = __uint_as_float(xu & 0x7fffffffu);
        float t   = __builtin_exp2f(a * -1.44269504088896340736f);
        float l2  = __builtin_log2f(1.0f + t);
        float pe  = fmaf(l2, 0.69314718055994530942f, fmaxf(sgn, 0.0f));
        float wg  = fmaf((float)bbit, 2.0f, 1.0f);       // BOUNDARY_WEIGHT=3
        acc = fmaf(wg, pe, acc);
    }
    return acc;
}

__global__ __launch_bounds__(BC_NT, 8)
void wbce_bce_kernel(const float* __restrict__ logits,
                     const uint2* __restrict__ tbnd,     // uint4 viewed as uint2
                     float* __restrict__ partial)
{
    __shared__ float sRed[BC_NWAVES];
    const int tid = threadIdx.x;
    const int t   = blockIdx.x * BC_NT + tid;            // float4 id of 1st half
    const float4* lg4 = (const float4*)logits;

    // 4 independent loads, issued back-to-back before any use
    float4 f0 = lg4[t];
    float4 f1 = lg4[t + BC_THREADS];
    uint2 tb0 = tbnd[t >> 3];                            // {target32, boundary32}
    uint2 tb1 = tbnd[(t >> 3) + (BC_THREADS >> 3)];
    const int sh = (t & 7) * 4;                          // same for both halves

    float acc = bce4(f0, tb0.x, tb0.y, sh) + bce4(f1, tb1.x, tb1.y, sh);

    // wave64 shuffle tree, then cross-wave via LDS, one partial per block
    #pragma unroll
    for (int off = 32; off > 0; off >>= 1)
        acc += __shfl_down(acc, off, 64);
    const int lane = tid & 63, wv = tid >> 6;
    if (lane == 0) sRed[wv] = acc;
    __syncthreads();
    if (tid == 0) {
        float s = 0.0f;
        #pragma unroll
        for (int i = 0; i < BC_NWAVES; ++i) s += sRed[i];
        partial[blockIdx.x] = s;
    }
}

// ============ kernel 4: final reduce of 8192 block partials ============
#define FR_NT 1024
__global__ __launch_bounds__(FR_NT, 1)
void wbce_final_kernel(const float* __restrict__ partial, float* __restrict__ out)
{
    __shared__ float sRed[FR_NT / 64];
    const int tid = threadIdx.x;
    const float4* p4 = (const float4*)partial;           // 2048 float4
    float4 a = p4[tid];
    float4 b = p4[tid + FR_NT];
    float acc = (a.x + a.y) + (a.z + a.w) + (b.x + b.y) + (b.z + b.w);
    #pragma unroll
    for (int off = 32; off > 0; off >>= 1)
        acc += __shfl_down(acc, off, 64);
    if ((tid & 63) == 0) sRed[tid >> 6] = acc;
    __syncthreads();
    if (tid == 0) {
        float s = 0.0f;
        #pragma unroll
        for (int i = 0; i < FR_NT / 64; ++i) s += sRed[i];
        out[0] = s * (1.0f / 16777216.0f);               // mean: 1/2^24 exact
    }
}

extern "C" void kernel_launch(void* const* d_in, const int* in_sizes, int n_in,
                              void* d_out, int out_size, void* d_ws, size_t ws_size,
                              hipStream_t stream) {
    const float* logits  = (const float*)d_in[0];
    const float* targets = (const float*)d_in[1];
    float* out = (float*)d_out;

    // scratch: pak 2MiB (u64) | tbnd 4MiB (uint4) | partials 32KiB (float)
    u64*   pak     = (u64*)d_ws;
    uint4* tbnd    = (uint4*)((char*)d_ws + (2u << 20));
    float* partial = (float*)((char*)d_ws + (6u << 20));

    // 1) pack targets into bitmask words
    wbce_pack_kernel<<<dim3(PK_BLOCKS), dim3(PK_NT), 0, stream>>>(targets, pak);

    // 2) bitwise 9x9 morphology on the 2MB packed array
    wbce_morph_kernel<<<dim3(TOTAL_WORDS / MO_NT), dim3(MO_NT), 0, stream>>>(pak, tbnd);

    // 3) BCE stream over logits -> per-block partials (no atomics)
    wbce_bce_kernel<<<dim3(BC_BLOCKS), dim3(BC_NT), 0, stream>>>(
        logits, (const uint2*)tbnd, partial);

    // 4) final reduce -> out[0] (overwrites; no zeroing needed anywhere)
    wbce_final_kernel<<<dim3(1), dim3(FR_NT), 0, stream>>>(partial, out);
}